// Round 4
// baseline (392.385 us; speedup 1.0000x reference)
//
#include <hip/hip_runtime.h>

// NoisyTopKRouter: x[4,4096,4096] f32, W[4096,8] f32, b[8] f32, noise[16384,8] f32
// out: top_k_weights [16384*2] | top_k_indices [16384*2] (as float) | aux_loss [1]
// Memory-bound: stream 256 MiB of x once. Floor ~43 us @ 6.3 TB/s.
//
// Structure: 1 block/CU (1024 thr, 128 KiB LDS for W, XOR-swizzled).
// Depth-3 register prefetch ring (continuous 12 loads in flight per wave,
// counted-vmcnt waits) + per-wave chunk-phase rotation (de-phase-locks the
// 16 waves; kills 16KB-stride L1-set aliasing across streams).

#define BS      16384
#define HDIM    4096
#define NE      8
#define RPW     4        // rows per wave
#define NWAVE   16       // waves per block (1024 threads)
#define NITER   16       // 1KB chunks per row (HDIM/4/64)
#define NOISE_EPS 0.01f
#define LB_COEFF  0.01f

__global__ __launch_bounds__(1024, 4)
void router_main(const float* __restrict__ x, const float* __restrict__ W,
                 const float* __restrict__ bias, const float* __restrict__ noise,
                 float* __restrict__ out, float* __restrict__ part) {
    const int tid  = threadIdx.x;
    const int lane = tid & 63;
    const int wave = tid >> 6;
    const int row0 = blockIdx.x * (NWAVE * RPW) + wave * RPW;

    // ---- W staged once, swizzled: float4-slot j of chunk f at j^(f&7) ----
    __shared__ float4 w_lds[HDIM * 2];      // 1024 chunks * 8 float4 = 128 KiB
    __shared__ float block_usage[NE];
    if (tid < NE) block_usage[tid] = 0.0f;
    {
        const float4* __restrict__ W4 = (const float4*)W;
        for (int i = tid; i < HDIM * 2; i += 1024) {
            const int f = i >> 3, j = i & 7;
            w_lds[(i & ~7) | (j ^ (f & 7))] = W4[i];
        }
    }
    __syncthreads();

    float acc[RPW][NE];
#pragma unroll
    for (int r = 0; r < RPW; ++r)
#pragma unroll
        for (int e = 0; e < NE; ++e) acc[r][e] = 0.0f;

    const float4* __restrict__ x4 = (const float4*)x + (size_t)row0 * (HDIM / 4);
    const int wxor = lane & 7;              // == chunk_f & 7 for every body

    float4 bufA[RPW], bufB[RPW], bufC[RPW];

// chunk index for body k, rotated per wave
#define CHUNKC(k) (((k) + wave) & 15)

#define LOADTO(BUF, k)                                                        \
    {                                                                         \
        const int o_ = CHUNKC(k) * 64 + lane;                                 \
        _Pragma("unroll")                                                     \
        for (int r = 0; r < RPW; ++r)                                         \
            BUF[r] = x4[r * (HDIM / 4) + o_];                                 \
    }

#define FMA_HALF(XC, F, KK)                                                   \
    {                                                                         \
        float4 wr[4];                                                         \
        _Pragma("unroll")                                                     \
        for (int m = 0; m < 4; ++m)                                           \
            wr[m] = w_lds[(F) * 8 + ((4 * (KK) + m) ^ wxor)];                 \
        _Pragma("unroll")                                                     \
        for (int r = 0; r < RPW; ++r) {                                       \
            _Pragma("unroll")                                                 \
            for (int kq = 0; kq < 2; ++kq) {                                  \
                const int k = 2 * (KK) + kq;                                  \
                const float xv = ((const float*)&XC[r])[k];                   \
                acc[r][0] += xv * wr[2 * kq].x;                               \
                acc[r][1] += xv * wr[2 * kq].y;                               \
                acc[r][2] += xv * wr[2 * kq].z;                               \
                acc[r][3] += xv * wr[2 * kq].w;                               \
                acc[r][4] += xv * wr[2 * kq + 1].x;                           \
                acc[r][5] += xv * wr[2 * kq + 1].y;                           \
                acc[r][6] += xv * wr[2 * kq + 1].z;                           \
                acc[r][7] += xv * wr[2 * kq + 1].w;                           \
            }                                                                 \
        }                                                                     \
    }

#define BODY(BUF, k)                                                          \
    {                                                                         \
        const int F_ = CHUNKC(k) * 64 + lane;                                 \
        FMA_HALF(BUF, F_, 0)                                                  \
        FMA_HALF(BUF, F_, 1)                                                  \
    }

    // prologue: fill the 3-deep ring
    LOADTO(bufA, 0)
    LOADTO(bufB, 1)
    LOADTO(bufC, 2)

#pragma unroll 1
    for (int s = 0; s < 4; ++s) {           // bodies 0..11, loads 3..14
        const int k0 = 3 * s;
        BODY(bufA, k0)     LOADTO(bufA, k0 + 3)
        BODY(bufB, k0 + 1) LOADTO(bufB, k0 + 4)
        BODY(bufC, k0 + 2) LOADTO(bufC, k0 + 5)
    }
    BODY(bufA, 12) LOADTO(bufA, 15)         // last load: chunk 15 -> A
    BODY(bufB, 13)
    BODY(bufC, 14)
    BODY(bufA, 15)

#undef BODY
#undef FMA_HALF
#undef LOADTO
#undef CHUNKC

    // ---- butterfly reduce the 32 partials across the 64-lane wave ----
#pragma unroll
    for (int r = 0; r < RPW; ++r)
#pragma unroll
        for (int e = 0; e < NE; ++e) {
            float v = acc[r][e];
#pragma unroll
            for (int m = 1; m < 64; m <<= 1) v += __shfl_xor(v, m, 64);
            acc[r][e] = v;
        }

    // ---- lanes 0..RPW-1 each own one row: epilogue in registers ----
    if (lane < RPW) {
        const int row = row0 + lane;

        float logits[NE];
#pragma unroll
        for (int r = 0; r < RPW; ++r)
            if (lane == r)
#pragma unroll
                for (int e = 0; e < NE; ++e) logits[e] = acc[r][e];

        const float4 b_lo = ((const float4*)bias)[0];
        const float4 b_hi = ((const float4*)bias)[1];
        const float4 n_lo = ((const float4*)(noise + (size_t)row * NE))[0];
        const float4 n_hi = ((const float4*)(noise + (size_t)row * NE))[1];

        logits[0] += b_lo.x + NOISE_EPS * n_lo.x;
        logits[1] += b_lo.y + NOISE_EPS * n_lo.y;
        logits[2] += b_lo.z + NOISE_EPS * n_lo.z;
        logits[3] += b_lo.w + NOISE_EPS * n_lo.w;
        logits[4] += b_hi.x + NOISE_EPS * n_hi.x;
        logits[5] += b_hi.y + NOISE_EPS * n_hi.y;
        logits[6] += b_hi.z + NOISE_EPS * n_hi.z;
        logits[7] += b_hi.w + NOISE_EPS * n_hi.w;

        float m = logits[0];
#pragma unroll
        for (int e = 1; e < NE; ++e) m = fmaxf(m, logits[e]);
        float p[NE], s = 0.0f;
#pragma unroll
        for (int e = 0; e < NE; ++e) { p[e] = expf(logits[e] - m); s += p[e]; }
        const float inv_s = 1.0f / s;

        float v1 = p[0]; int e1 = 0;
#pragma unroll
        for (int e = 1; e < NE; ++e) if (p[e] > v1) { v1 = p[e]; e1 = e; }
        float v2 = -1.0f; int e2 = 0;
#pragma unroll
        for (int e = 0; e < NE; ++e)
            if (e != e1 && p[e] > v2) { v2 = p[e]; e2 = e; }

        const float inv_d = 1.0f / (v1 + v2);
        out[(size_t)row * 2]     = v1 * inv_d;
        out[(size_t)row * 2 + 1] = v2 * inv_d;
        out[(size_t)(BS * 2) + row * 2]     = (float)e1;
        out[(size_t)(BS * 2) + row * 2 + 1] = (float)e2;

#pragma unroll
        for (int e = 0; e < NE; ++e)
            atomicAdd(&block_usage[e], p[e] * inv_s);
    }

    __syncthreads();
    // per-block partial usage -> d_ws (no global atomics, no memset needed)
    if (tid < NE) part[blockIdx.x * NE + tid] = block_usage[tid];
}

__global__ void router_finalize(const float* __restrict__ part,
                                float* __restrict__ out) {
    // one wave: lane l sums blocks 4l..4l+3 of all 8 experts, then butterfly
    const int lane = threadIdx.x & 63;
    float p[NE];
#pragma unroll
    for (int e = 0; e < NE; ++e) p[e] = 0.0f;
#pragma unroll
    for (int j = 0; j < 4; ++j) {
        const int b = lane * 4 + j;
#pragma unroll
        for (int e = 0; e < NE; ++e) p[e] += part[b * NE + e];
    }
#pragma unroll
    for (int e = 0; e < NE; ++e) {
        float v = p[e];
#pragma unroll
        for (int m = 1; m < 64; m <<= 1) v += __shfl_xor(v, m, 64);
        p[e] = v;
    }
    if (lane == 0) {
        float aux = 0.0f;
#pragma unroll
        for (int e = 0; e < NE; ++e) {
            const float mean = p[e] * (1.0f / (float)BS);
            const float d = mean - (1.0f / (float)NE);
            aux += d * d;
        }
        out[(size_t)BS * 4] = LB_COEFF * aux;
    }
}

extern "C" void kernel_launch(void* const* d_in, const int* in_sizes, int n_in,
                              void* d_out, int out_size, void* d_ws, size_t ws_size,
                              hipStream_t stream) {
    const float* x     = (const float*)d_in[0];   // [4,4096,4096]
    const float* W     = (const float*)d_in[1];   // [4096,8]
    const float* b     = (const float*)d_in[2];   // [8]
    const float* noise = (const float*)d_in[3];   // [16384,8]
    float* out  = (float*)d_out;
    float* part = (float*)d_ws;                   // 256*8 floats of partials

    const int blocks = BS / (NWAVE * RPW);        // 256 blocks of 1024 threads
    router_main<<<blocks, 1024, 0, stream>>>(x, W, b, noise, out, part);
    router_finalize<<<1, 64, 0, stream>>>(part, out);
}

// Round 5
// 369.318 us; speedup vs baseline: 1.0625x; 1.0625x over previous
//
#include <hip/hip_runtime.h>

// NoisyTopKRouter: x[4,4096,4096] f32, W[4096,8] f32, b[8] f32, noise[16384,8] f32
// out: top_k_weights [16384*2] | top_k_indices [16384*2] (as float) | aux_loss [1]
// Memory-bound: stream 256 MiB of x once. Floor ~43 us @ 6.3 TB/s.
//
// R5 structure: RPW=1 (one row per wave; acc=8, ring=16 VGPR -> no spill
// possible under the 128-reg cap), 1024 blocks x 1024 thr (4 sequential
// block-waves/CU -> dispatch imbalance penalty 2.0x -> 1.25x). W staged once
// per block into 128 KiB LDS, XOR-swizzled (conflict-free ds_read_b128).
// 4-deep static register ring on the x-stream (4 KB in flight per wave).

#define BS      16384
#define HDIM    4096
#define NE      8
#define NWAVE   16       // waves per block (1024 threads); 1 row per wave
#define NOISE_EPS 0.01f
#define LB_COEFF  0.01f

__global__ __launch_bounds__(1024, 4)
void router_main(const float* __restrict__ x, const float* __restrict__ W,
                 const float* __restrict__ bias, const float* __restrict__ noise,
                 float* __restrict__ out, float* __restrict__ part) {
    const int tid  = threadIdx.x;
    const int lane = tid & 63;
    const int wave = tid >> 6;
    const int row  = blockIdx.x * NWAVE + wave;

    // ---- W staged once, swizzled: float4-slot j of chunk-row f at j^(f&7) ----
    __shared__ float4 w_lds[HDIM * 2];      // 4096 h-rows * 2 float4 = 128 KiB
    __shared__ float block_usage[NE];
    if (tid < NE) block_usage[tid] = 0.0f;
    {
        const float4* __restrict__ W4 = (const float4*)W;
        for (int i = tid; i < HDIM * 2; i += 1024) {
            const int f = i >> 3, j = i & 7;
            w_lds[(i & ~7) | (j ^ (f & 7))] = W4[i];
        }
    }
    __syncthreads();

    float acc[NE];
#pragma unroll
    for (int e = 0; e < NE; ++e) acc[e] = 0.0f;

    const float4* __restrict__ x4 = (const float4*)x + (size_t)row * (HDIM / 4);
    const int wxor = lane & 7;              // == F & 7 for every body

    float4 b0, b1, b2, b3;

#define LOADTO(B, k) B = x4[(k) * 64 + lane];

#define BODY(B, k)                                                            \
    {                                                                         \
        const int F_ = (k) * 64 + lane;                                       \
        float4 wr[8];                                                         \
        _Pragma("unroll")                                                     \
        for (int m = 0; m < 8; ++m)                                           \
            wr[m] = w_lds[F_ * 8 + (m ^ wxor)];                               \
        _Pragma("unroll")                                                     \
        for (int k4 = 0; k4 < 4; ++k4) {                                      \
            const float xv = ((const float*)&B)[k4];                          \
            acc[0] += xv * wr[2 * k4].x;                                      \
            acc[1] += xv * wr[2 * k4].y;                                      \
            acc[2] += xv * wr[2 * k4].z;                                      \
            acc[3] += xv * wr[2 * k4].w;                                      \
            acc[4] += xv * wr[2 * k4 + 1].x;                                  \
            acc[5] += xv * wr[2 * k4 + 1].y;                                  \
            acc[6] += xv * wr[2 * k4 + 1].z;                                  \
            acc[7] += xv * wr[2 * k4 + 1].w;                                  \
        }                                                                     \
    }

    // prologue: fill the 4-deep ring (4 KB in flight per wave)
    LOADTO(b0, 0)
    LOADTO(b1, 1)
    LOADTO(b2, 2)
    LOADTO(b3, 3)

#pragma unroll 1
    for (int s = 0; s < 3; ++s) {           // bodies 0..11, loads 4..15
        const int k0 = 4 * s;
        BODY(b0, k0)     LOADTO(b0, k0 + 4)
        BODY(b1, k0 + 1) LOADTO(b1, k0 + 5)
        BODY(b2, k0 + 2) LOADTO(b2, k0 + 6)
        BODY(b3, k0 + 3) LOADTO(b3, k0 + 7)
    }
    BODY(b0, 12)
    BODY(b1, 13)
    BODY(b2, 14)
    BODY(b3, 15)

#undef BODY
#undef LOADTO

    // ---- butterfly reduce the 8 partials across the 64-lane wave ----
#pragma unroll
    for (int e = 0; e < NE; ++e) {
        float v = acc[e];
#pragma unroll
        for (int m = 1; m < 64; m <<= 1) v += __shfl_xor(v, m, 64);
        acc[e] = v;
    }

    // ---- lane 0 of each wave owns the row: epilogue in registers ----
    if (lane == 0) {
        float logits[NE];
#pragma unroll
        for (int e = 0; e < NE; ++e) logits[e] = acc[e];

        const float4 b_lo = ((const float4*)bias)[0];
        const float4 b_hi = ((const float4*)bias)[1];
        const float4 n_lo = ((const float4*)(noise + (size_t)row * NE))[0];
        const float4 n_hi = ((const float4*)(noise + (size_t)row * NE))[1];

        logits[0] += b_lo.x + NOISE_EPS * n_lo.x;
        logits[1] += b_lo.y + NOISE_EPS * n_lo.y;
        logits[2] += b_lo.z + NOISE_EPS * n_lo.z;
        logits[3] += b_lo.w + NOISE_EPS * n_lo.w;
        logits[4] += b_hi.x + NOISE_EPS * n_hi.x;
        logits[5] += b_hi.y + NOISE_EPS * n_hi.y;
        logits[6] += b_hi.z + NOISE_EPS * n_hi.z;
        logits[7] += b_hi.w + NOISE_EPS * n_hi.w;

        float m = logits[0];
#pragma unroll
        for (int e = 1; e < NE; ++e) m = fmaxf(m, logits[e]);
        float p[NE], s = 0.0f;
#pragma unroll
        for (int e = 0; e < NE; ++e) { p[e] = expf(logits[e] - m); s += p[e]; }
        const float inv_s = 1.0f / s;

        float v1 = p[0]; int e1 = 0;
#pragma unroll
        for (int e = 1; e < NE; ++e) if (p[e] > v1) { v1 = p[e]; e1 = e; }
        float v2 = -1.0f; int e2 = 0;
#pragma unroll
        for (int e = 0; e < NE; ++e)
            if (e != e1 && p[e] > v2) { v2 = p[e]; e2 = e; }

        const float inv_d = 1.0f / (v1 + v2);
        out[(size_t)row * 2]     = v1 * inv_d;
        out[(size_t)row * 2 + 1] = v2 * inv_d;
        out[(size_t)(BS * 2) + row * 2]     = (float)e1;
        out[(size_t)(BS * 2) + row * 2 + 1] = (float)e2;

#pragma unroll
        for (int e = 0; e < NE; ++e)
            atomicAdd(&block_usage[e], p[e] * inv_s);
    }

    __syncthreads();
    // per-block partial usage -> d_ws (no global atomics, no memset needed)
    if (tid < NE) part[blockIdx.x * NE + tid] = block_usage[tid];
}

__global__ void router_finalize(const float* __restrict__ part,
                                float* __restrict__ out) {
    // one wave: lane l sums blocks {l, l+64, ...} then butterfly-reduces
    const int lane = threadIdx.x & 63;
    float p[NE];
#pragma unroll
    for (int e = 0; e < NE; ++e) p[e] = 0.0f;
    for (int j = 0; j < 16; ++j) {
        const int b = j * 64 + lane;
#pragma unroll
        for (int e = 0; e < NE; ++e) p[e] += part[b * NE + e];
    }
#pragma unroll
    for (int e = 0; e < NE; ++e) {
        float v = p[e];
#pragma unroll
        for (int m = 1; m < 64; m <<= 1) v += __shfl_xor(v, m, 64);
        p[e] = v;
    }
    if (lane == 0) {
        float aux = 0.0f;
#pragma unroll
        for (int e = 0; e < NE; ++e) {
            const float mean = p[e] * (1.0f / (float)BS);
            const float d = mean - (1.0f / (float)NE);
            aux += d * d;
        }
        out[(size_t)BS * 4] = LB_COEFF * aux;
    }
}

extern "C" void kernel_launch(void* const* d_in, const int* in_sizes, int n_in,
                              void* d_out, int out_size, void* d_ws, size_t ws_size,
                              hipStream_t stream) {
    const float* x     = (const float*)d_in[0];   // [4,4096,4096]
    const float* W     = (const float*)d_in[1];   // [4096,8]
    const float* b     = (const float*)d_in[2];   // [8]
    const float* noise = (const float*)d_in[3];   // [16384,8]
    float* out  = (float*)d_out;
    float* part = (float*)d_ws;                   // 1024*8 floats of partials

    const int blocks = BS / NWAVE;                // 1024 blocks of 1024 threads
    router_main<<<blocks, 1024, 0, stream>>>(x, W, b, noise, out, part);
    router_finalize<<<1, 64, 0, stream>>>(part, out);
}